// Round 1
// baseline (1419.690 us; speedup 1.0000x reference)
//
#include <hip/hip_runtime.h>

#define VOCAB  256
#define EMBED  32
#define HIDDEN 32
#define LAYERS 10
#define BATCH  1024
#define SEQ    1024

// Persistent layer-pipeline kernel.
// One block = 2 batch elements, 640 threads = 10 waves, wave w owns layer w.
// Wave lanes: jj = lane&31 (hidden unit), bh = lane>>5 (which batch elem).
// Each thread keeps its layer's W_ih/W_hh row (64 VGPRs) for the whole run.
// Layer handoff via double-buffered LDS slots; ONE barrier per pipeline step.
__global__ __launch_bounds__(640, 1) void rnn_pipeline(
    const int* __restrict__ x, const float* __restrict__ emb,
    const float* __restrict__ W_ih, const float* __restrict__ W_hh,
    const float* __restrict__ b_ih, const float* __restrict__ b_hh,
    float* __restrict__ h_out /* [BATCH][HIDDEN] scratch */)
{
    __shared__ __align__(16) float slot[LAYERS][2][2][HIDDEN]; // [layer][parity][bh][j]
    __shared__ int x_lds[2][SEQ];

    const int tid  = threadIdx.x;
    const int w    = tid >> 6;        // wave index == layer
    const int lane = tid & 63;
    const int bh   = lane >> 5;       // 0/1: which of the block's 2 batch elems
    const int jj   = lane & 31;       // hidden unit this lane produces
    const int b    = blockIdx.x * 2 + bh;

    // Stage this block's two token rows into LDS (cooperative, coalesced).
    for (int idx = tid; idx < 2 * SEQ; idx += 640) {
        const int bb = idx >> 10, tt = idx & (SEQ - 1);
        x_lds[bb][tt] = x[(blockIdx.x * 2 + bb) * SEQ + tt];
    }
    // Zero-init h-state slots (h0 = 0).
    for (int idx = tid; idx < LAYERS * 2 * 2 * HIDDEN; idx += 640)
        ((float*)slot)[idx] = 0.0f;

    // Preload this wave's layer weights: row jj of W_ih[w] and W_hh[w].
    float4 Wih[8], Whh[8];
    {
        const float4* wi = (const float4*)(W_ih + (w * HIDDEN + jj) * EMBED);
        const float4* wh = (const float4*)(W_hh + (w * HIDDEN + jj) * HIDDEN);
        #pragma unroll
        for (int c = 0; c < 8; ++c) { Wih[c] = wi[c]; Whh[c] = wh[c]; }
    }
    const float bias = b_ih[w * HIDDEN + jj] + b_hh[w * HIDDEN + jj];

    __syncthreads();  // x_lds + slot zero-init visible to everyone

    // Wave 0: prefetch embedding row for t=0 (used inside iter 0).
    float4 nxt[8];
    if (w == 0) {
        const int tok = x_lds[bh][0];
        const float4* er = (const float4*)(emb + tok * EMBED);
        #pragma unroll
        for (int c = 0; c < 8; ++c) nxt[c] = er[c];
    }

    const int NIT = SEQ + LAYERS - 1;  // pipeline fill + steady + drain
    for (int it = 0; it < NIT; ++it) {
        __syncthreads();               // the single per-step barrier
        const int t = it - w;
        const bool act = (t >= 0) && (t < SEQ);   // wave-uniform predicate
        if (act) {
            const int rp = (it + 1) & 1;  // parity written LAST iter
            const int wp = it & 1;        // parity we write THIS iter

            float acc = bias;

            if (w == 0) {
                // consume prefetched embedding row directly from registers
                #pragma unroll
                for (int c = 0; c < 8; ++c) {
                    acc += Wih[c].x * nxt[c].x; acc += Wih[c].y * nxt[c].y;
                    acc += Wih[c].z * nxt[c].z; acc += Wih[c].w * nxt[c].w;
                }
                // prefetch t+1 (latency hidden by one pipeline step)
                if (t + 1 < SEQ) {
                    const int tok = x_lds[bh][t + 1];
                    const float4* er = (const float4*)(emb + tok * EMBED);
                    #pragma unroll
                    for (int c = 0; c < 8; ++c) nxt[c] = er[c];
                }
            } else {
                // input = previous layer's output (broadcast LDS reads)
                const float4* sr = (const float4*)(&slot[w - 1][rp][bh][0]);
                #pragma unroll
                for (int c = 0; c < 8; ++c) {
                    const float4 a = sr[c];
                    acc += Wih[c].x * a.x; acc += Wih[c].y * a.y;
                    acc += Wih[c].z * a.z; acc += Wih[c].w * a.w;
                }
            }

            // recurrent term: own layer's h from last timestep
            {
                const float4* hr = (const float4*)(&slot[w][rp][bh][0]);
                #pragma unroll
                for (int c = 0; c < 8; ++c) {
                    const float4 hv = hr[c];
                    acc += Whh[c].x * hv.x; acc += Whh[c].y * hv.y;
                    acc += Whh[c].z * hv.z; acc += Whh[c].w * hv.w;
                }
            }

            const float h = tanhf(acc);
            slot[w][wp][bh][jj] = h;
            if (w == LAYERS - 1 && t == SEQ - 1)
                h_out[b * HIDDEN + jj] = h;   // final hidden of top layer
        }
    }
}

// Epilogue: out[b][v] = h_fin[b][:] . W_fc[v][:] + b_fc[v]
__global__ __launch_bounds__(256) void rnn_fc(
    const float* __restrict__ h_fin, const float* __restrict__ W_fc,
    const float* __restrict__ b_fc, float* __restrict__ out)
{
    const int b = blockIdx.x;
    const int v = threadIdx.x;
    const float4* hr = (const float4*)(h_fin + b * HIDDEN);
    const float4* wr = (const float4*)(W_fc + v * HIDDEN);
    float acc = b_fc[v];
    #pragma unroll
    for (int c = 0; c < 8; ++c) {
        const float4 hv = hr[c], wv = wr[c];
        acc += hv.x * wv.x + hv.y * wv.y + hv.z * wv.z + hv.w * wv.w;
    }
    out[b * VOCAB + v] = acc;
}

extern "C" void kernel_launch(void* const* d_in, const int* in_sizes, int n_in,
                              void* d_out, int out_size, void* d_ws, size_t ws_size,
                              hipStream_t stream) {
    const int*   x    = (const int*)d_in[0];
    const float* emb  = (const float*)d_in[1];
    const float* W_ih = (const float*)d_in[2];
    const float* W_hh = (const float*)d_in[3];
    const float* b_ih = (const float*)d_in[4];
    const float* b_hh = (const float*)d_in[5];
    const float* W_fc = (const float*)d_in[6];
    const float* b_fc = (const float*)d_in[7];
    float* out   = (float*)d_out;
    float* h_fin = (float*)d_ws;    // BATCH*HIDDEN floats = 128 KB scratch

    rnn_pipeline<<<BATCH / 2, 640, 0, stream>>>(x, emb, W_ih, W_hh, b_ih, b_hh, h_fin);
    rnn_fc<<<BATCH, VOCAB, 0, stream>>>(h_fin, W_fc, b_fc, out);
}

// Round 2
// 735.771 us; speedup vs baseline: 1.9295x; 1.9295x over previous
//
#include <hip/hip_runtime.h>

#define VOCAB  256
#define EMBED  32
#define HIDDEN 32
#define LAYERS 10
#define BATCH  1024
#define SEQ    1024

typedef _Float16 h2 __attribute__((ext_vector_type(2)));

__device__ __forceinline__ h2 u2h(unsigned u) { return __builtin_bit_cast(h2, u); }
__device__ __forceinline__ unsigned h2u(h2 h) { return __builtin_bit_cast(unsigned, h); }

// f16x2 dot with f32 accumulate: v_dot2_f32_f16 (2 MACs / instr).
__device__ __forceinline__ float dot2(unsigned a, unsigned b, float acc) {
#if __has_builtin(__builtin_amdgcn_fdot2)
    return __builtin_amdgcn_fdot2(u2h(a), u2h(b), acc, false);
#else
    h2 x = u2h(a), y = u2h(b);
    acc += (float)x[0] * (float)y[0];
    acc += (float)x[1] * (float)y[1];
    return acc;
#endif
}

// Persistent layer-pipeline kernel, fp16-pair math.
// Block = 2 batch elems, 640 threads = 10 waves, wave w owns layer w.
// Weights live in 32 packed-f16 VGPRs per thread (asm-pinned, no remat).
// h vectors handed off through LDS as f16 (64 B per vector).
// Wave 0 doubles as embedding feeder: slot s=0 holds the f16 input vector,
// prefetched 2 iterations ahead (1 VGPR), so layer 0 reads LDS like all layers.
__global__ __launch_bounds__(640, 2) void rnn_pipeline(
    const int* __restrict__ x, const float* __restrict__ emb,
    const float* __restrict__ W_ih, const float* __restrict__ W_hh,
    const float* __restrict__ b_ih, const float* __restrict__ b_hh,
    float* __restrict__ h_out /* [BATCH][HIDDEN] scratch */)
{
    // vec[parity][bh][slot][16 u32]: slot 0 = embedding input, slot l+1 = layer l output.
    __shared__ unsigned vec[2][2][LAYERS + 1][16];
    __shared__ int x_lds[2][SEQ];

    const int tid  = threadIdx.x;
    const int w    = tid >> 6;        // wave index == layer
    const int lane = tid & 63;
    const int bh   = lane >> 5;       // which of the block's 2 batch elems
    const int jj   = lane & 31;       // hidden unit this lane produces
    const int b    = blockIdx.x * 2 + bh;

    // Stage token rows (coalesced).
    for (int idx = tid; idx < 2 * SEQ; idx += 640) {
        const int bb = idx >> 10, tt = idx & (SEQ - 1);
        x_lds[bb][tt] = x[(blockIdx.x * 2 + bb) * SEQ + tt];
    }
    // Zero-init h slots (h0 = 0; f16 zero == bit zero).
    for (int idx = tid; idx < 2 * 2 * (LAYERS + 1) * 16; idx += 640)
        ((unsigned*)vec)[idx] = 0u;

    // Preload + convert this wave's weight rows to packed f16 pairs.
    unsigned wih[16], whh[16];
    {
        const float4* wi = (const float4*)(W_ih + (w * HIDDEN + jj) * EMBED);
        const float4* wh = (const float4*)(W_hh + (w * HIDDEN + jj) * HIDDEN);
        #pragma unroll
        for (int c = 0; c < 8; ++c) {
            const float4 a = wi[c], d = wh[c];
            wih[2 * c]     = h2u(h2{(_Float16)a.x, (_Float16)a.y});
            wih[2 * c + 1] = h2u(h2{(_Float16)a.z, (_Float16)a.w});
            whh[2 * c]     = h2u(h2{(_Float16)d.x, (_Float16)d.y});
            whh[2 * c + 1] = h2u(h2{(_Float16)d.z, (_Float16)d.w});
        }
    }
    // Pin: forbids rematerialization (round-1 failure mode: VGPR=72 => W reloaded each iter).
    #pragma unroll
    for (int i = 0; i < 16; ++i) {
        asm volatile("" : "+v"(wih[i]));
        asm volatile("" : "+v"(whh[i]));
    }
    const float bias = b_ih[w * HIDDEN + jj] + b_hh[w * HIDDEN + jj];

    __syncthreads();  // x_lds + zero-init visible

    // Feeder prologue: emb(t=0) -> parity 1; emb(t=1) -> nxt reg.
    unsigned nxt = 0;
    if (w == 0 && jj < 16) {
        const int tok0 = x_lds[bh][0];
        const float2 e0 = *(const float2*)(emb + tok0 * EMBED + 2 * jj);
        vec[1][bh][0][jj] = h2u(h2{(_Float16)e0.x, (_Float16)e0.y});
        const int tok1 = x_lds[bh][1];
        const float2 e1 = *(const float2*)(emb + tok1 * EMBED + 2 * jj);
        nxt = h2u(h2{(_Float16)e1.x, (_Float16)e1.y});
    }

    const int NIT = SEQ + LAYERS - 1;
    for (int it = 0; it < NIT; ++it) {
        __syncthreads();               // the single per-step barrier
        const int t = it - w;
        if (t < 0 || t >= SEQ) continue;   // wave-uniform
        const int rp = (it + 1) & 1;  // parity written last iter (read now)
        const int wp = it & 1;        // parity we write now

        if (w == 0) {
            // publish emb(t+1) for next iter; prefetch emb(t+2).
            if (jj < 16 && t + 1 < SEQ) vec[wp][bh][0][jj] = nxt;
            if (jj < 16 && t + 2 < SEQ) {
                const int tok = x_lds[bh][t + 2];
                const float2 e2 = *(const float2*)(emb + tok * EMBED + 2 * jj);
                nxt = h2u(h2{(_Float16)e2.x, (_Float16)e2.y});
            }
        }

        // input vector (slot w) and own recurrent h (slot w+1): broadcast b128 reads.
        const uint4* ip = (const uint4*)&vec[rp][bh][w][0];
        const uint4* hp = (const uint4*)&vec[rp][bh][w + 1][0];
        float a0 = bias, a1 = 0.f;
        #pragma unroll
        for (int c = 0; c < 4; ++c) {
            const uint4 iv = ip[c];
            a0 = dot2(iv.x, wih[4 * c + 0], a0);
            a0 = dot2(iv.y, wih[4 * c + 1], a0);
            a0 = dot2(iv.z, wih[4 * c + 2], a0);
            a0 = dot2(iv.w, wih[4 * c + 3], a0);
        }
        #pragma unroll
        for (int c = 0; c < 4; ++c) {
            const uint4 hv = hp[c];
            a1 = dot2(hv.x, whh[4 * c + 0], a1);
            a1 = dot2(hv.y, whh[4 * c + 1], a1);
            a1 = dot2(hv.z, whh[4 * c + 2], a1);
            a1 = dot2(hv.w, whh[4 * c + 3], a1);
        }
        const float acc = a0 + a1;

        // tanh(x) = 1 - 2/(1 + e^{2x}); robust at +/-inf, ~1e-6 abs err.
        const float e = __expf(acc + acc);
        const float r = __builtin_amdgcn_rcpf(1.0f + e);
        const float hval = 1.0f - (r + r);

        ((_Float16*)&vec[wp][bh][w + 1][0])[jj] = (_Float16)hval;
        if (w == LAYERS - 1 && t == SEQ - 1)
            h_out[b * HIDDEN + jj] = hval;   // final hidden of top layer (f32)
    }
}

// Epilogue: out[b][v] = h_fin[b][:] . W_fc[v][:] + b_fc[v]  (fp32, unchanged)
__global__ __launch_bounds__(256) void rnn_fc(
    const float* __restrict__ h_fin, const float* __restrict__ W_fc,
    const float* __restrict__ b_fc, float* __restrict__ out)
{
    const int b = blockIdx.x;
    const int v = threadIdx.x;
    const float4* hr = (const float4*)(h_fin + b * HIDDEN);
    const float4* wr = (const float4*)(W_fc + v * HIDDEN);
    float acc = b_fc[v];
    #pragma unroll
    for (int c = 0; c < 8; ++c) {
        const float4 hv = hr[c], wv = wr[c];
        acc += hv.x * wv.x + hv.y * wv.y + hv.z * wv.z + hv.w * wv.w;
    }
    out[b * VOCAB + v] = acc;
}

extern "C" void kernel_launch(void* const* d_in, const int* in_sizes, int n_in,
                              void* d_out, int out_size, void* d_ws, size_t ws_size,
                              hipStream_t stream) {
    const int*   x    = (const int*)d_in[0];
    const float* emb  = (const float*)d_in[1];
    const float* W_ih = (const float*)d_in[2];
    const float* W_hh = (const float*)d_in[3];
    const float* b_ih = (const float*)d_in[4];
    const float* b_hh = (const float*)d_in[5];
    const float* W_fc = (const float*)d_in[6];
    const float* b_fc = (const float*)d_in[7];
    float* out   = (float*)d_out;
    float* h_fin = (float*)d_ws;    // BATCH*HIDDEN floats = 128 KB scratch

    rnn_pipeline<<<BATCH / 2, 640, 0, stream>>>(x, emb, W_ih, W_hh, b_ih, b_hh, h_fin);
    rnn_fc<<<BATCH, VOCAB, 0, stream>>>(h_fin, W_fc, b_fc, out);
}